// Round 6
// baseline (1467.370 us; speedup 1.0000x reference)
//
#include <hip/hip_runtime.h>
#include <cstdint>
#include <cfloat>
#include <cstddef>

#define C_   128
#define CH   64
#define B_   8
#define S_   6
#define H_   128
#define W_   192
#define HW   (H_*W_)          /* 24576 */
#define SHW  (S_*HW)          /* 147456 */
#define NPIX (B_*SHW)         /* 1179648 */
#define KTOP 100
#define CAP  6144
#define NEGV (-1e9f)
#define EPSV (1e-6f)
#define CPAD 64               /* counts padded: one counter per 256B */

// ---------------------------------------------------------------------------
// K1: resp = sigma^2 * ( w2 . relu(W1 @ feat + b1) + b2 )
// Round 6: explicit 4-deep prefetch of the streaming f loads (latency ~900cy
// < 1024 VALU cycles per 4-c body). Accumulation order unchanged vs Round 5
// (bit-exact absmax=0 preserved). launch_bounds(256,3) keeps 3 waves/SIMD.
// ---------------------------------------------------------------------------
__global__ __launch_bounds__(256, 3) void resp_kernel(
    const float* __restrict__ feats, const float* __restrict__ sigma,
    const float* __restrict__ w1, const float* __restrict__ b1,
    const float* __restrict__ w2, const float* __restrict__ b2,
    float* __restrict__ resp)
{
    __shared__ float w1t[C_ * CH];   // [c][o]
    __shared__ float b1s[CH];
    __shared__ float w2s[CH];

    for (int i = threadIdx.x; i < C_ * CH; i += 256) {
        int o = i & (CH - 1);
        int c = i >> 6;
        w1t[i] = w1[o * C_ + c];
    }
    if (threadIdx.x < CH) {
        b1s[threadIdx.x] = b1[threadIdx.x];
        w2s[threadIdx.x] = w2[threadIdx.x];
    }
    __syncthreads();

    const int plane = blockIdx.x / 48;              // b*S + s
    const int p0    = (blockIdx.x % 48) * 512 + threadIdx.x * 2;
    const float* fp = feats + (size_t)plane * (size_t)(C_ * HW) + p0;

    float2 acc[CH];
#pragma unroll
    for (int o = 0; o < CH; ++o) { acc[o].x = 0.f; acc[o].y = 0.f; }

#define LDF(cc) (*reinterpret_cast<const float2*>(fp + (size_t)(cc) * HW))
#define STEP(fv, cc)                                                         \
    {                                                                        \
        _Pragma("unroll")                                                    \
        for (int o = 0; o < CH; o += 4) {                                    \
            const float4 w = *reinterpret_cast<const float4*>(               \
                &w1t[((cc) << 6) + o]);                                      \
            acc[o + 0].x += w.x * fv.x;  acc[o + 0].y += w.x * fv.y;         \
            acc[o + 1].x += w.y * fv.x;  acc[o + 1].y += w.y * fv.y;         \
            acc[o + 2].x += w.z * fv.x;  acc[o + 2].y += w.z * fv.y;         \
            acc[o + 3].x += w.w * fv.x;  acc[o + 3].y += w.w * fv.y;         \
        }                                                                    \
    }

    float2 f0 = LDF(0);
    float2 f1 = LDF(1);
    float2 f2 = LDF(2);
    float2 f3 = LDF(3);

    for (int c = 0; c < C_; c += 4) {
        // prefetch next 4 channel-planes (wraps to 0 on the tail: harmless
        // redundant in-bounds loads, keeps the loop branchless)
        float2 n0 = LDF((c + 4) & 127);
        float2 n1 = LDF((c + 5) & 127);
        float2 n2 = LDF((c + 6) & 127);
        float2 n3 = LDF((c + 7) & 127);
        STEP(f0, c + 0)
        STEP(f1, c + 1)
        STEP(f2, c + 2)
        STEP(f3, c + 3)
        f0 = n0; f1 = n1; f2 = n2; f3 = n3;
    }
#undef STEP
#undef LDF

    const float b2v = b2[0];
    float rx = b2v, ry = b2v;
#pragma unroll
    for (int o = 0; o < CH; ++o) {
        float hx = fmaxf(acc[o].x + b1s[o], 0.f);
        float hy = fmaxf(acc[o].y + b1s[o], 0.f);
        rx += w2s[o] * hx;
        ry += w2s[o] * hy;
    }
    const int   s   = plane % S_;
    const float sg  = sigma[s];
    const float sg2 = sg * sg;
    float2 outv; outv.x = rx * sg2; outv.y = ry * sg2;
    *reinterpret_cast<float2*>(resp + (size_t)plane * HW + p0) = outv;
}

// ---------------------------------------------------------------------------
// K2: 3x3x3 local max -> candidates. Per-block LDS aggregation, ONE global
// atomic per block, counters padded to separate cache lines.
// ---------------------------------------------------------------------------
__global__ __launch_bounds__(256) void peak_kernel(
    const float* __restrict__ resp, int* __restrict__ counts,
    float* __restrict__ cscore, int* __restrict__ cidx)
{
    __shared__ int   lcount;
    __shared__ int   lbase;
    __shared__ float lsc[256];
    __shared__ int   lsi[256];

    if (threadIdx.x == 0) lcount = 0;
    __syncthreads();

    const int gid = blockIdx.x * 256 + threadIdx.x;   // grid covers NPIX exactly
    const int b   = gid / SHW;                        // uniform per block
    const int rem = gid - b * SHW;
    const int s   = rem / HW;                         // uniform per block
    const int p   = rem - s * HW;
    const int y   = p / W_;
    const int x   = p - y * W_;

    const float v = resp[gid];
    bool win = false;
    if (v > 0.f) {                         // is_peak requires resp > 0
        float m = NEGV;
        for (int ds = -1; ds <= 1; ++ds) {
            const int ss = s + ds;
            if (ss < 0 || ss >= S_) continue;   // NEG padding contributes nothing
            for (int dy = -1; dy <= 1; ++dy) {
                const int yy = y + dy;
                if (yy < 0 || yy >= H_) continue;
                for (int dx = -1; dx <= 1; ++dx) {
                    const int xx = x + dx;
                    if (xx < 0 || xx >= W_) continue;
                    m = fmaxf(m, resp[(b * S_ + ss) * HW + yy * W_ + xx]);
                }
            }
        }
        // m includes v itself, so m >= v and |v - m| = m - v
        win = (m - v < EPSV);
    }

    if (win) {
        const int lp = atomicAdd(&lcount, 1);   // LDS atomic — cheap
        lsc[lp] = v;
        lsi[lp] = s * HW + p;
    }
    __syncthreads();
    if (threadIdx.x == 0 && lcount > 0)
        lbase = atomicAdd(&counts[b * CPAD], lcount);  // one atomic/block, padded line
    __syncthreads();
    const int n = lcount;
    for (int i = threadIdx.x; i < n; i += 256) {
        const int pos = lbase + i;
        if (pos < CAP) {
            cscore[b * CAP + pos] = lsc[i];
            cidx[b * CAP + pos]   = lsi[i];
        }
    }
}

// ---------------------------------------------------------------------------
// K3: per-batch top-100 by (score desc, flat idx asc) — matches lax.top_k ties
// ---------------------------------------------------------------------------
__global__ __launch_bounds__(1024) void topk_kernel(
    const float* __restrict__ cscore, const int* __restrict__ cidx,
    const int* __restrict__ counts, const float* __restrict__ sigma,
    float* __restrict__ out)
{
    __shared__ float sc[CAP];
    __shared__ int   si[CAP];
    __shared__ float rs[16];
    __shared__ int   ri[16];
    __shared__ int   rp[16];

    const int b    = blockIdx.x;
    const int tid  = threadIdx.x;
    const int wid  = tid >> 6;
    const int lane = tid & 63;

    int cnt = counts[b * CPAD];
    if (cnt > CAP) cnt = CAP;

    for (int i = tid; i < cnt; i += 1024) {
        sc[i] = cscore[b * CAP + i];
        si[i] = cidx[b * CAP + i];
    }
    __syncthreads();

    for (int k = 0; k < KTOP; ++k) {
        float bs = -FLT_MAX;
        int   bi = 0x7fffffff;
        int   bp = -1;
        for (int i = tid; i < cnt; i += 1024) {
            const float s_ = sc[i];
            const int   id = si[i];
            if (s_ > bs || (s_ == bs && id < bi)) { bs = s_; bi = id; bp = i; }
        }
#pragma unroll
        for (int off = 32; off > 0; off >>= 1) {
            const float os = __shfl_xor(bs, off);
            const int   oi = __shfl_xor(bi, off);
            const int   op = __shfl_xor(bp, off);
            if (os > bs || (os == bs && oi < bi)) { bs = os; bi = oi; bp = op; }
        }
        if (lane == 0) { rs[wid] = bs; ri[wid] = bi; rp[wid] = bp; }
        __syncthreads();
        if (tid == 0) {
            float fb = rs[0]; int fi = ri[0]; int fpos = rp[0];
            for (int wv = 1; wv < 16; ++wv) {
                if (rs[wv] > fb || (rs[wv] == fb && ri[wv] < fi)) {
                    fb = rs[wv]; fi = ri[wv]; fpos = rp[wv];
                }
            }
            float scorev; int flatidx;
            if (fpos < 0) {                 // fewer than K candidates (not expected)
                scorev = NEGV; flatidx = (k - cnt) > 0 ? (k - cnt) : 0;
            } else {
                scorev = fb; flatidx = fi;
                sc[fpos] = -FLT_MAX;        // remove winner
            }
            int sidx = flatidx / HW;
            if (sidx < 0) sidx = 0; if (sidx > S_ - 1) sidx = S_ - 1;
            const int sp = flatidx - (flatidx / HW) * HW;
            const int yy = sp / W_;
            const int xx = sp - yy * W_;
            out[b * KTOP + k]                  = fmaxf(scorev, 0.f);
            out[800 + (b * KTOP + k) * 2 + 0]  = (float)xx / (float)W_;
            out[800 + (b * KTOP + k) * 2 + 1]  = (float)yy / (float)H_;
            out[2400 + b * KTOP + k]           = sigma[sidx];
            out[3200 + b * KTOP + k]           = (float)sp;
        }
        __syncthreads();
    }
}

__global__ void init_counts_kernel(int* counts)
{
    for (int i = threadIdx.x; i < B_ * CPAD; i += 256) counts[i] = 0;
}

extern "C" void kernel_launch(void* const* d_in, const int* in_sizes, int n_in,
                              void* d_out, int out_size, void* d_ws, size_t ws_size,
                              hipStream_t stream)
{
    const float* feats = (const float*)d_in[0];
    const float* sigma = (const float*)d_in[1];
    const float* w1    = (const float*)d_in[2];
    const float* b1    = (const float*)d_in[3];
    const float* w2    = (const float*)d_in[4];
    const float* b2    = (const float*)d_in[5];
    float* out = (float*)d_out;

    char* ws = (char*)d_ws;
    float* resp   = (float*)ws;
    int*   counts = (int*)(ws + (size_t)NPIX * 4);                       // B_*CPAD ints
    float* cscore = (float*)(ws + (size_t)NPIX * 4 + (size_t)B_ * CPAD * 4);
    int*   cidx   = (int*)(ws + (size_t)NPIX * 4 + (size_t)B_ * CPAD * 4
                              + (size_t)B_ * CAP * 4);

    init_counts_kernel<<<1, 256, 0, stream>>>(counts);
    resp_kernel<<<2304, 256, 0, stream>>>(feats, sigma, w1, b1, w2, b2, resp);
    peak_kernel<<<NPIX / 256, 256, 0, stream>>>(resp, counts, cscore, cidx);
    topk_kernel<<<B_, 1024, 0, stream>>>(cscore, cidx, counts, sigma, out);
}

// Round 7
// 538.722 us; speedup vs baseline: 2.7238x; 2.7238x over previous
//
#include <hip/hip_runtime.h>
#include <cstdint>
#include <cfloat>
#include <cstddef>

#define C_   128
#define CH   64
#define B_   8
#define S_   6
#define H_   128
#define W_   192
#define HW   (H_*W_)          /* 24576 */
#define SHW  (S_*HW)          /* 147456 */
#define NPIX (B_*SHW)         /* 1179648 */
#define KTOP 100
#define CAP  6144
#define NEGV (-1e9f)
#define EPSV (1e-6f)
#define CPAD 64               /* counts padded: one counter per 256B */
#define NBIN 2048
#define FCAP 4096

// ---------------------------------------------------------------------------
// K1: resp = sigma^2 * ( w2 . relu(W1 @ feat + b1) + b2 )
// EXACT Round-5 version (measured 387us, absmax=0). NO launch_bounds min-wave
// arg: Round 6 showed (256,3) + deep prefetch => VGPR clamp 108->84 + 2.1GB
// scratch spill (WRITE_SIZE) => 3x slower.
// ---------------------------------------------------------------------------
__global__ __launch_bounds__(256) void resp_kernel(
    const float* __restrict__ feats, const float* __restrict__ sigma,
    const float* __restrict__ w1, const float* __restrict__ b1,
    const float* __restrict__ w2, const float* __restrict__ b2,
    float* __restrict__ resp)
{
    __shared__ float w1t[C_ * CH];   // [c][o]
    __shared__ float b1s[CH];
    __shared__ float w2s[CH];

    for (int i = threadIdx.x; i < C_ * CH; i += 256) {
        int o = i & (CH - 1);
        int c = i >> 6;
        w1t[i] = w1[o * C_ + c];
    }
    if (threadIdx.x < CH) {
        b1s[threadIdx.x] = b1[threadIdx.x];
        w2s[threadIdx.x] = w2[threadIdx.x];
    }
    __syncthreads();

    const int plane = blockIdx.x / 48;              // b*S + s
    const int p0    = (blockIdx.x % 48) * 512 + threadIdx.x * 2;
    const float* fp = feats + (size_t)plane * (size_t)(C_ * HW) + p0;

    float2 acc[CH];
#pragma unroll
    for (int o = 0; o < CH; ++o) { acc[o].x = 0.f; acc[o].y = 0.f; }

#pragma unroll 2
    for (int c = 0; c < C_; ++c) {
        const float2 f = *reinterpret_cast<const float2*>(fp + c * HW);
#pragma unroll
        for (int o = 0; o < CH; o += 4) {
            const float4 w = *reinterpret_cast<const float4*>(&w1t[(c << 6) + o]);
            acc[o + 0].x += w.x * f.x;  acc[o + 0].y += w.x * f.y;
            acc[o + 1].x += w.y * f.x;  acc[o + 1].y += w.y * f.y;
            acc[o + 2].x += w.z * f.x;  acc[o + 2].y += w.z * f.y;
            acc[o + 3].x += w.w * f.x;  acc[o + 3].y += w.w * f.y;
        }
    }

    const float b2v = b2[0];
    float rx = b2v, ry = b2v;
#pragma unroll
    for (int o = 0; o < CH; ++o) {
        float hx = fmaxf(acc[o].x + b1s[o], 0.f);
        float hy = fmaxf(acc[o].y + b1s[o], 0.f);
        rx += w2s[o] * hx;
        ry += w2s[o] * hy;
    }
    const int   s   = plane % S_;
    const float sg  = sigma[s];
    const float sg2 = sg * sg;
    float2 outv; outv.x = rx * sg2; outv.y = ry * sg2;
    *reinterpret_cast<float2*>(resp + (size_t)plane * HW + p0) = outv;
}

// ---------------------------------------------------------------------------
// K2: 3x3x3 local max -> candidates. Per-block LDS aggregation, ONE global
// atomic per block, counters padded to separate cache lines (Round-5 fix).
// ---------------------------------------------------------------------------
__global__ __launch_bounds__(256) void peak_kernel(
    const float* __restrict__ resp, int* __restrict__ counts,
    float* __restrict__ cscore, int* __restrict__ cidx)
{
    __shared__ int   lcount;
    __shared__ int   lbase;
    __shared__ float lsc[256];
    __shared__ int   lsi[256];

    if (threadIdx.x == 0) lcount = 0;
    __syncthreads();

    const int gid = blockIdx.x * 256 + threadIdx.x;   // grid covers NPIX exactly
    const int b   = gid / SHW;                        // uniform per block
    const int rem = gid - b * SHW;
    const int s   = rem / HW;                         // uniform per block
    const int p   = rem - s * HW;
    const int y   = p / W_;
    const int x   = p - y * W_;

    const float v = resp[gid];
    bool win = false;
    if (v > 0.f) {                         // is_peak requires resp > 0
        float m = NEGV;
        for (int ds = -1; ds <= 1; ++ds) {
            const int ss = s + ds;
            if (ss < 0 || ss >= S_) continue;   // NEG padding contributes nothing
            for (int dy = -1; dy <= 1; ++dy) {
                const int yy = y + dy;
                if (yy < 0 || yy >= H_) continue;
                for (int dx = -1; dx <= 1; ++dx) {
                    const int xx = x + dx;
                    if (xx < 0 || xx >= W_) continue;
                    m = fmaxf(m, resp[(b * S_ + ss) * HW + yy * W_ + xx]);
                }
            }
        }
        // m includes v itself, so m >= v and |v - m| = m - v
        win = (m - v < EPSV);
    }

    if (win) {
        const int lp = atomicAdd(&lcount, 1);   // LDS atomic — cheap
        lsc[lp] = v;
        lsi[lp] = s * HW + p;
    }
    __syncthreads();
    if (threadIdx.x == 0 && lcount > 0)
        lbase = atomicAdd(&counts[b * CPAD], lcount);  // one atomic/block, padded line
    __syncthreads();
    const int n = lcount;
    for (int i = threadIdx.x; i < n; i += 256) {
        const int pos = lbase + i;
        if (pos < CAP) {
            cscore[b * CAP + pos] = lsc[i];
            cidx[b * CAP + pos]   = lsi[i];
        }
    }
}

// ---------------------------------------------------------------------------
// K3 v2: histogram radix-select (Round 7). Positive floats order as uints.
// Stage A: 2048-bin histogram of score bits [31:20].
// Stage B: walk bins top-down to find the bin containing rank min(cnt,100).
// Stage C: compact candidates with bin >= B into LDS finalists (~150-250).
// Stage D: exact top-100 over finalists, ONE wave, zero barriers, tie-break
//          (score desc, flat idx asc) — identical selection to lax.top_k.
// Replaces the 100x block-wide-argmax version measured at ~270us.
// ---------------------------------------------------------------------------
__global__ __launch_bounds__(256) void topk_kernel(
    const float* __restrict__ cscore, const int* __restrict__ cidx,
    const int* __restrict__ counts, const float* __restrict__ sigma,
    float* __restrict__ out)
{
    __shared__ int   hist[NBIN];
    __shared__ float fsc[FCAP];
    __shared__ int   fid[FCAP];
    __shared__ int   nf_sh;
    __shared__ int   binB_sh;

    const int b   = blockIdx.x;
    const int tid = threadIdx.x;

    int cnt = counts[b * CPAD];
    if (cnt > CAP) cnt = CAP;
    const int need = cnt < KTOP ? cnt : KTOP;

    for (int i = tid; i < NBIN; i += 256) hist[i] = 0;
    if (tid == 0) nf_sh = 0;
    __syncthreads();

    // Stage A: histogram (scores are >0 so float bits are uint-monotone)
    for (int i = tid; i < cnt; i += 256) {
        const unsigned u = __float_as_uint(cscore[b * CAP + i]);
        atomicAdd(&hist[u >> 20], 1);
    }
    __syncthreads();

    // Stage B: find threshold bin (serial walk, ~2048 iters, negligible)
    if (tid == 0) {
        int cum = 0, B = 0;
        for (int bin = NBIN - 1; bin >= 0; --bin) {
            cum += hist[bin];
            if (cum >= need) { B = bin; break; }
        }
        binB_sh = B;
    }
    __syncthreads();
    const int B = binB_sh;

    // Stage C: compact finalists (set-based; LDS-atomic order irrelevant)
    for (int i = tid; i < cnt; i += 256) {
        const float s_ = cscore[b * CAP + i];
        const unsigned u = __float_as_uint(s_);
        if ((int)(u >> 20) >= B) {
            const int p = atomicAdd(&nf_sh, 1);
            if (p < FCAP) { fsc[p] = s_; fid[p] = cidx[b * CAP + i]; }
        }
    }
    __syncthreads();
    int nf = nf_sh;
    if (nf > FCAP) nf = FCAP;

    // Stage D: one wave, exact iterative top-100 over finalists
    if (tid < 64) {
        const int lane = tid;
        for (int k = 0; k < KTOP; ++k) {
            if (k < need) {
                float bs = -FLT_MAX;
                int   bi = 0x7fffffff;
                int   bp = -1;
                for (int i = lane; i < nf; i += 64) {
                    const float s_ = fsc[i];
                    const int   id = fid[i];
                    if (s_ > bs || (s_ == bs && id < bi)) { bs = s_; bi = id; bp = i; }
                }
#pragma unroll
                for (int off = 32; off > 0; off >>= 1) {
                    const float os = __shfl_xor(bs, off);
                    const int   oi = __shfl_xor(bi, off);
                    const int   op = __shfl_xor(bp, off);
                    if (os > bs || (os == bs && oi < bi)) { bs = os; bi = oi; bp = op; }
                }
                // winner slot is only ever scanned by lane (bp&63): same-lane
                // LDS dependency, no cross-lane sync needed
                if (bp >= 0 && (bp & 63) == lane) fsc[bp] = -FLT_MAX;
                if (lane == 0) {
                    const int sidx = bi / HW;
                    const int sp   = bi - sidx * HW;
                    const int yy   = sp / W_;
                    const int xx   = sp - yy * W_;
                    const int sc_c = sidx < 0 ? 0 : (sidx > S_ - 1 ? S_ - 1 : sidx);
                    out[b * KTOP + k]                 = bs > 0.f ? bs : 0.f;
                    out[800 + (b * KTOP + k) * 2 + 0] = (float)xx / (float)W_;
                    out[800 + (b * KTOP + k) * 2 + 1] = (float)yy / (float)H_;
                    out[2400 + b * KTOP + k]          = sigma[sc_c];
                    out[3200 + b * KTOP + k]          = (float)sp;
                }
            } else if (lane == 0) {
                // cnt < 100 fallback (not expected for this input): NEG entries
                int flat = k - cnt; if (flat < 0) flat = 0;
                const int sidx = flat / HW;
                const int sp   = flat - sidx * HW;
                const int yy   = sp / W_;
                const int xx   = sp - yy * W_;
                const int sc_c = sidx < 0 ? 0 : (sidx > S_ - 1 ? S_ - 1 : sidx);
                out[b * KTOP + k]                 = 0.f;
                out[800 + (b * KTOP + k) * 2 + 0] = (float)xx / (float)W_;
                out[800 + (b * KTOP + k) * 2 + 1] = (float)yy / (float)H_;
                out[2400 + b * KTOP + k]          = sigma[sc_c];
                out[3200 + b * KTOP + k]          = (float)sp;
            }
        }
    }
}

__global__ void init_counts_kernel(int* counts)
{
    for (int i = threadIdx.x; i < B_ * CPAD; i += 256) counts[i] = 0;
}

extern "C" void kernel_launch(void* const* d_in, const int* in_sizes, int n_in,
                              void* d_out, int out_size, void* d_ws, size_t ws_size,
                              hipStream_t stream)
{
    const float* feats = (const float*)d_in[0];
    const float* sigma = (const float*)d_in[1];
    const float* w1    = (const float*)d_in[2];
    const float* b1    = (const float*)d_in[3];
    const float* w2    = (const float*)d_in[4];
    const float* b2    = (const float*)d_in[5];
    float* out = (float*)d_out;

    char* ws = (char*)d_ws;
    float* resp   = (float*)ws;
    int*   counts = (int*)(ws + (size_t)NPIX * 4);                       // B_*CPAD ints
    float* cscore = (float*)(ws + (size_t)NPIX * 4 + (size_t)B_ * CPAD * 4);
    int*   cidx   = (int*)(ws + (size_t)NPIX * 4 + (size_t)B_ * CPAD * 4
                              + (size_t)B_ * CAP * 4);

    init_counts_kernel<<<1, 256, 0, stream>>>(counts);
    resp_kernel<<<2304, 256, 0, stream>>>(feats, sigma, w1, b1, w2, b2, resp);
    peak_kernel<<<NPIX / 256, 256, 0, stream>>>(resp, counts, cscore, cidx);
    topk_kernel<<<B_, 256, 0, stream>>>(cscore, cidx, counts, sigma, out);
}

// Round 8
// 455.030 us; speedup vs baseline: 3.2248x; 1.1839x over previous
//
#include <hip/hip_runtime.h>
#include <cstdint>
#include <cfloat>
#include <cstddef>

#define C_   128
#define CH   64
#define B_   8
#define S_   6
#define H_   128
#define W_   192
#define HW   (H_*W_)          /* 24576 */
#define SHW  (S_*HW)          /* 147456 */
#define NPIX (B_*SHW)         /* 1179648 */
#define KTOP 100
#define CAP  6144
#define NEGV (-1e9f)
#define EPSV (1e-6f)
#define CPAD 64               /* counts padded: one counter per 256B */
#define NBIN 2048
#define FCAP 4096

// ---------------------------------------------------------------------------
// K0b: transpose w1 (CHxC row-major) -> w1t_g (CxCH) once per launch, so the
// resp kernel can read it with block-UNIFORM contiguous indices (scalar pipe).
// ---------------------------------------------------------------------------
__global__ __launch_bounds__(256) void transpose_w1_kernel(
    const float* __restrict__ w1, float* __restrict__ w1t_g)
{
    const int i = blockIdx.x * 256 + threadIdx.x;   // grid covers C_*CH exactly
    const int c = i >> 6;           // [0,128)
    const int o = i & (CH - 1);     // [0,64)
    w1t_g[i] = w1[o * C_ + c];
}

// ---------------------------------------------------------------------------
// K1 v3: resp = sigma^2 * ( w2 . relu(W1 @ feat + b1) + b2 )
// Round 8 change: w1t moved LDS -> global with wave-uniform reads (compiler
// scalarizes to s_load; w feeds v_fma as the SGPR operand). Kills the 16
// ds_read_b128/c-iter LDS pipe load AND the 33KB LDS occupancy cap seen in
// Round 7 (Occupancy 21%, VALUBusy 48%). FMA order per acc unchanged
// (bit-exact vs Rounds 4-7, absmax=0). NO launch_bounds min-wave arg
// (Round 6: (256,3) caused VGPR clamp + 2.1GB scratch spill).
// ---------------------------------------------------------------------------
__global__ __launch_bounds__(256) void resp_kernel(
    const float* __restrict__ feats, const float* __restrict__ sigma,
    const float* __restrict__ w1t_g, const float* __restrict__ b1,
    const float* __restrict__ w2, const float* __restrict__ b2,
    float* __restrict__ resp)
{
    __shared__ float b1s[CH];
    __shared__ float w2s[CH];
    if (threadIdx.x < CH) {
        b1s[threadIdx.x] = b1[threadIdx.x];
        w2s[threadIdx.x] = w2[threadIdx.x];
    }
    __syncthreads();

    const int plane = blockIdx.x / 48;              // b*S + s
    const int p0    = (blockIdx.x % 48) * 512 + threadIdx.x * 2;
    const float* fp = feats + (size_t)plane * (size_t)(C_ * HW) + p0;

    float2 acc[CH];
#pragma unroll
    for (int o = 0; o < CH; ++o) { acc[o].x = 0.f; acc[o].y = 0.f; }

#pragma unroll 2
    for (int c = 0; c < C_; ++c) {
        const float2 f = *reinterpret_cast<const float2*>(fp + c * HW);
#pragma unroll
        for (int o = 0; o < CH; o += 4) {
            // block-uniform address -> scalar load; w.* are SGPR operands
            const float4 w = *reinterpret_cast<const float4*>(
                &w1t_g[(c << 6) + o]);
            acc[o + 0].x += w.x * f.x;  acc[o + 0].y += w.x * f.y;
            acc[o + 1].x += w.y * f.x;  acc[o + 1].y += w.y * f.y;
            acc[o + 2].x += w.z * f.x;  acc[o + 2].y += w.z * f.y;
            acc[o + 3].x += w.w * f.x;  acc[o + 3].y += w.w * f.y;
        }
    }

    const float b2v = b2[0];
    float rx = b2v, ry = b2v;
#pragma unroll
    for (int o = 0; o < CH; ++o) {
        float hx = fmaxf(acc[o].x + b1s[o], 0.f);
        float hy = fmaxf(acc[o].y + b1s[o], 0.f);
        rx += w2s[o] * hx;
        ry += w2s[o] * hy;
    }
    const int   s   = plane % S_;
    const float sg  = sigma[s];
    const float sg2 = sg * sg;
    float2 outv; outv.x = rx * sg2; outv.y = ry * sg2;
    *reinterpret_cast<float2*>(resp + (size_t)plane * HW + p0) = outv;
}

// ---------------------------------------------------------------------------
// K2: 3x3x3 local max -> candidates. Per-block LDS aggregation, ONE global
// atomic per block, counters padded to separate cache lines (Round-5 fix).
// ---------------------------------------------------------------------------
__global__ __launch_bounds__(256) void peak_kernel(
    const float* __restrict__ resp, int* __restrict__ counts,
    float* __restrict__ cscore, int* __restrict__ cidx)
{
    __shared__ int   lcount;
    __shared__ int   lbase;
    __shared__ float lsc[256];
    __shared__ int   lsi[256];

    if (threadIdx.x == 0) lcount = 0;
    __syncthreads();

    const int gid = blockIdx.x * 256 + threadIdx.x;   // grid covers NPIX exactly
    const int b   = gid / SHW;                        // uniform per block
    const int rem = gid - b * SHW;
    const int s   = rem / HW;                         // uniform per block
    const int p   = rem - s * HW;
    const int y   = p / W_;
    const int x   = p - y * W_;

    const float v = resp[gid];
    bool win = false;
    if (v > 0.f) {                         // is_peak requires resp > 0
        float m = NEGV;
        for (int ds = -1; ds <= 1; ++ds) {
            const int ss = s + ds;
            if (ss < 0 || ss >= S_) continue;   // NEG padding contributes nothing
            for (int dy = -1; dy <= 1; ++dy) {
                const int yy = y + dy;
                if (yy < 0 || yy >= H_) continue;
                for (int dx = -1; dx <= 1; ++dx) {
                    const int xx = x + dx;
                    if (xx < 0 || xx >= W_) continue;
                    m = fmaxf(m, resp[(b * S_ + ss) * HW + yy * W_ + xx]);
                }
            }
        }
        // m includes v itself, so m >= v and |v - m| = m - v
        win = (m - v < EPSV);
    }

    if (win) {
        const int lp = atomicAdd(&lcount, 1);   // LDS atomic — cheap
        lsc[lp] = v;
        lsi[lp] = s * HW + p;
    }
    __syncthreads();
    if (threadIdx.x == 0 && lcount > 0)
        lbase = atomicAdd(&counts[b * CPAD], lcount);  // one atomic/block, padded line
    __syncthreads();
    const int n = lcount;
    for (int i = threadIdx.x; i < n; i += 256) {
        const int pos = lbase + i;
        if (pos < CAP) {
            cscore[b * CAP + pos] = lsc[i];
            cidx[b * CAP + pos]   = lsi[i];
        }
    }
}

// ---------------------------------------------------------------------------
// K3 v2: histogram radix-select (Round 7, measured good). Exact lax.top_k
// semantics: (score desc, flat idx asc).
// ---------------------------------------------------------------------------
__global__ __launch_bounds__(256) void topk_kernel(
    const float* __restrict__ cscore, const int* __restrict__ cidx,
    const int* __restrict__ counts, const float* __restrict__ sigma,
    float* __restrict__ out)
{
    __shared__ int   hist[NBIN];
    __shared__ float fsc[FCAP];
    __shared__ int   fid[FCAP];
    __shared__ int   nf_sh;
    __shared__ int   binB_sh;

    const int b   = blockIdx.x;
    const int tid = threadIdx.x;

    int cnt = counts[b * CPAD];
    if (cnt > CAP) cnt = CAP;
    const int need = cnt < KTOP ? cnt : KTOP;

    for (int i = tid; i < NBIN; i += 256) hist[i] = 0;
    if (tid == 0) nf_sh = 0;
    __syncthreads();

    // Stage A: histogram (scores are >0 so float bits are uint-monotone)
    for (int i = tid; i < cnt; i += 256) {
        const unsigned u = __float_as_uint(cscore[b * CAP + i]);
        atomicAdd(&hist[u >> 20], 1);
    }
    __syncthreads();

    // Stage B: find threshold bin (serial walk, ~2048 iters, negligible)
    if (tid == 0) {
        int cum = 0, B = 0;
        for (int bin = NBIN - 1; bin >= 0; --bin) {
            cum += hist[bin];
            if (cum >= need) { B = bin; break; }
        }
        binB_sh = B;
    }
    __syncthreads();
    const int B = binB_sh;

    // Stage C: compact finalists (set-based; LDS-atomic order irrelevant)
    for (int i = tid; i < cnt; i += 256) {
        const float s_ = cscore[b * CAP + i];
        const unsigned u = __float_as_uint(s_);
        if ((int)(u >> 20) >= B) {
            const int p = atomicAdd(&nf_sh, 1);
            if (p < FCAP) { fsc[p] = s_; fid[p] = cidx[b * CAP + i]; }
        }
    }
    __syncthreads();
    int nf = nf_sh;
    if (nf > FCAP) nf = FCAP;

    // Stage D: one wave, exact iterative top-100 over finalists
    if (tid < 64) {
        const int lane = tid;
        for (int k = 0; k < KTOP; ++k) {
            if (k < need) {
                float bs = -FLT_MAX;
                int   bi = 0x7fffffff;
                int   bp = -1;
                for (int i = lane; i < nf; i += 64) {
                    const float s_ = fsc[i];
                    const int   id = fid[i];
                    if (s_ > bs || (s_ == bs && id < bi)) { bs = s_; bi = id; bp = i; }
                }
#pragma unroll
                for (int off = 32; off > 0; off >>= 1) {
                    const float os = __shfl_xor(bs, off);
                    const int   oi = __shfl_xor(bi, off);
                    const int   op = __shfl_xor(bp, off);
                    if (os > bs || (os == bs && oi < bi)) { bs = os; bi = oi; bp = op; }
                }
                // winner slot is only ever scanned by lane (bp&63): same-lane
                // LDS dependency, no cross-lane sync needed
                if (bp >= 0 && (bp & 63) == lane) fsc[bp] = -FLT_MAX;
                if (lane == 0) {
                    const int sidx = bi / HW;
                    const int sp   = bi - sidx * HW;
                    const int yy   = sp / W_;
                    const int xx   = sp - yy * W_;
                    const int sc_c = sidx < 0 ? 0 : (sidx > S_ - 1 ? S_ - 1 : sidx);
                    out[b * KTOP + k]                 = bs > 0.f ? bs : 0.f;
                    out[800 + (b * KTOP + k) * 2 + 0] = (float)xx / (float)W_;
                    out[800 + (b * KTOP + k) * 2 + 1] = (float)yy / (float)H_;
                    out[2400 + b * KTOP + k]          = sigma[sc_c];
                    out[3200 + b * KTOP + k]          = (float)sp;
                }
            } else if (lane == 0) {
                // cnt < 100 fallback (not expected for this input): NEG entries
                int flat = k - cnt; if (flat < 0) flat = 0;
                const int sidx = flat / HW;
                const int sp   = flat - sidx * HW;
                const int yy   = sp / W_;
                const int xx   = sp - yy * W_;
                const int sc_c = sidx < 0 ? 0 : (sidx > S_ - 1 ? S_ - 1 : sidx);
                out[b * KTOP + k]                 = 0.f;
                out[800 + (b * KTOP + k) * 2 + 0] = (float)xx / (float)W_;
                out[800 + (b * KTOP + k) * 2 + 1] = (float)yy / (float)H_;
                out[2400 + b * KTOP + k]          = sigma[sc_c];
                out[3200 + b * KTOP + k]          = (float)sp;
            }
        }
    }
}

__global__ void init_counts_kernel(int* counts)
{
    for (int i = threadIdx.x; i < B_ * CPAD; i += 256) counts[i] = 0;
}

extern "C" void kernel_launch(void* const* d_in, const int* in_sizes, int n_in,
                              void* d_out, int out_size, void* d_ws, size_t ws_size,
                              hipStream_t stream)
{
    const float* feats = (const float*)d_in[0];
    const float* sigma = (const float*)d_in[1];
    const float* w1    = (const float*)d_in[2];
    const float* b1    = (const float*)d_in[3];
    const float* w2    = (const float*)d_in[4];
    const float* b2    = (const float*)d_in[5];
    float* out = (float*)d_out;

    char* ws = (char*)d_ws;
    float* resp   = (float*)ws;
    int*   counts = (int*)(ws + (size_t)NPIX * 4);                       // B_*CPAD ints
    float* cscore = (float*)(ws + (size_t)NPIX * 4 + (size_t)B_ * CPAD * 4);
    int*   cidx   = (int*)(ws + (size_t)NPIX * 4 + (size_t)B_ * CPAD * 4
                              + (size_t)B_ * CAP * 4);
    float* w1t_g  = (float*)(ws + (size_t)NPIX * 4 + (size_t)B_ * CPAD * 4
                              + (size_t)B_ * CAP * 4 + (size_t)B_ * CAP * 4);

    init_counts_kernel<<<1, 256, 0, stream>>>(counts);
    transpose_w1_kernel<<<C_ * CH / 256, 256, 0, stream>>>(w1, w1t_g);
    resp_kernel<<<2304, 256, 0, stream>>>(feats, sigma, w1t_g, b1, w2, b2, resp);
    peak_kernel<<<NPIX / 256, 256, 0, stream>>>(resp, counts, cscore, cidx);
    topk_kernel<<<B_, 256, 0, stream>>>(cscore, cidx, counts, sigma, out);
}

// Round 9
// 423.065 us; speedup vs baseline: 3.4684x; 1.0756x over previous
//
#include <hip/hip_runtime.h>
#include <cstdint>
#include <cfloat>
#include <cstddef>

#define C_   128
#define CH   64
#define B_   8
#define S_   6
#define H_   128
#define W_   192
#define HW   (H_*W_)          /* 24576 */
#define SHW  (S_*HW)          /* 147456 */
#define NPIX (B_*SHW)         /* 1179648 */
#define KTOP 100
#define CAP  6144
#define NEGV (-1e9f)
#define EPSV (1e-6f)
#define CPAD 64               /* counts padded: one counter per 256B */
#define NBIN 2048
#define FCAP 4096

// ---------------------------------------------------------------------------
// K0b: transpose w1 (CHxC row-major) -> w1t_g (CxCH) once per launch, so the
// resp kernel can read it with block-UNIFORM contiguous indices (scalar pipe).
// ---------------------------------------------------------------------------
__global__ __launch_bounds__(256) void transpose_w1_kernel(
    const float* __restrict__ w1, float* __restrict__ w1t_g)
{
    const int i = blockIdx.x * 256 + threadIdx.x;   // grid covers C_*CH exactly
    const int c = i >> 6;           // [0,128)
    const int o = i & (CH - 1);     // [0,64)
    w1t_g[i] = w1[o * C_ + c];
}

// ---------------------------------------------------------------------------
// K1 v4: resp = sigma^2 * ( w2 . relu(W1 @ feat + b1) + b2 )
// Round 9 change: 1 pixel/thread (was 2). acc[] halves 128->64 VGPRs =>
// ~80 VGPR => 6 waves/SIMD (was 4 at VGPR=108). FMA chain per pixel is
// IDENTICAL to the previous .x lane (c ascending, o ascending, same
// epilogue) => bit-exact, absmax stays 0. w1t stays scalar-pipe (uniform
// global reads, Round-8 win). NO launch_bounds min-wave arg (Round-6
// spill pitfall); spill tripwire = WRITE_SIZE ballooning.
// ---------------------------------------------------------------------------
__global__ __launch_bounds__(256) void resp_kernel(
    const float* __restrict__ feats, const float* __restrict__ sigma,
    const float* __restrict__ w1t_g, const float* __restrict__ b1,
    const float* __restrict__ w2, const float* __restrict__ b2,
    float* __restrict__ resp)
{
    __shared__ float b1s[CH];
    __shared__ float w2s[CH];
    if (threadIdx.x < CH) {
        b1s[threadIdx.x] = b1[threadIdx.x];
        w2s[threadIdx.x] = w2[threadIdx.x];
    }
    __syncthreads();

    const int plane = blockIdx.x / 96;              // b*S + s   (96 blk/plane)
    const int p0    = (blockIdx.x % 96) * 256 + threadIdx.x;
    const float* fp = feats + (size_t)plane * (size_t)(C_ * HW) + p0;

    float acc[CH];
#pragma unroll
    for (int o = 0; o < CH; ++o) acc[o] = 0.f;

#pragma unroll 4
    for (int c = 0; c < C_; ++c) {
        const float f = fp[(size_t)c * HW];         // wave: 64x4B contiguous
#pragma unroll
        for (int o = 0; o < CH; o += 4) {
            // block-uniform address -> scalar load; w.* are SGPR operands
            const float4 w = *reinterpret_cast<const float4*>(
                &w1t_g[(c << 6) + o]);
            acc[o + 0] += w.x * f;
            acc[o + 1] += w.y * f;
            acc[o + 2] += w.z * f;
            acc[o + 3] += w.w * f;
        }
    }

    const float b2v = b2[0];
    float rx = b2v;
#pragma unroll
    for (int o = 0; o < CH; ++o) {
        const float hx = fmaxf(acc[o] + b1s[o], 0.f);
        rx += w2s[o] * hx;
    }
    const int   s   = plane % S_;
    const float sg  = sigma[s];
    resp[(size_t)plane * HW + p0] = rx * (sg * sg);
}

// ---------------------------------------------------------------------------
// K2: 3x3x3 local max -> candidates. Per-block LDS aggregation, ONE global
// atomic per block, counters padded to separate cache lines (Round-5 fix).
// ---------------------------------------------------------------------------
__global__ __launch_bounds__(256) void peak_kernel(
    const float* __restrict__ resp, int* __restrict__ counts,
    float* __restrict__ cscore, int* __restrict__ cidx)
{
    __shared__ int   lcount;
    __shared__ int   lbase;
    __shared__ float lsc[256];
    __shared__ int   lsi[256];

    if (threadIdx.x == 0) lcount = 0;
    __syncthreads();

    const int gid = blockIdx.x * 256 + threadIdx.x;   // grid covers NPIX exactly
    const int b   = gid / SHW;                        // uniform per block
    const int rem = gid - b * SHW;
    const int s   = rem / HW;                         // uniform per block
    const int p   = rem - s * HW;
    const int y   = p / W_;
    const int x   = p - y * W_;

    const float v = resp[gid];
    bool win = false;
    if (v > 0.f) {                         // is_peak requires resp > 0
        float m = NEGV;
        for (int ds = -1; ds <= 1; ++ds) {
            const int ss = s + ds;
            if (ss < 0 || ss >= S_) continue;   // NEG padding contributes nothing
            for (int dy = -1; dy <= 1; ++dy) {
                const int yy = y + dy;
                if (yy < 0 || yy >= H_) continue;
                for (int dx = -1; dx <= 1; ++dx) {
                    const int xx = x + dx;
                    if (xx < 0 || xx >= W_) continue;
                    m = fmaxf(m, resp[(b * S_ + ss) * HW + yy * W_ + xx]);
                }
            }
        }
        // m includes v itself, so m >= v and |v - m| = m - v
        win = (m - v < EPSV);
    }

    if (win) {
        const int lp = atomicAdd(&lcount, 1);   // LDS atomic — cheap
        lsc[lp] = v;
        lsi[lp] = s * HW + p;
    }
    __syncthreads();
    if (threadIdx.x == 0 && lcount > 0)
        lbase = atomicAdd(&counts[b * CPAD], lcount);  // one atomic/block, padded line
    __syncthreads();
    const int n = lcount;
    for (int i = threadIdx.x; i < n; i += 256) {
        const int pos = lbase + i;
        if (pos < CAP) {
            cscore[b * CAP + pos] = lsc[i];
            cidx[b * CAP + pos]   = lsi[i];
        }
    }
}

// ---------------------------------------------------------------------------
// K3 v2: histogram radix-select (Round 7, measured good). Exact lax.top_k
// semantics: (score desc, flat idx asc).
// ---------------------------------------------------------------------------
__global__ __launch_bounds__(256) void topk_kernel(
    const float* __restrict__ cscore, const int* __restrict__ cidx,
    const int* __restrict__ counts, const float* __restrict__ sigma,
    float* __restrict__ out)
{
    __shared__ int   hist[NBIN];
    __shared__ float fsc[FCAP];
    __shared__ int   fid[FCAP];
    __shared__ int   nf_sh;
    __shared__ int   binB_sh;

    const int b   = blockIdx.x;
    const int tid = threadIdx.x;

    int cnt = counts[b * CPAD];
    if (cnt > CAP) cnt = CAP;
    const int need = cnt < KTOP ? cnt : KTOP;

    for (int i = tid; i < NBIN; i += 256) hist[i] = 0;
    if (tid == 0) nf_sh = 0;
    __syncthreads();

    // Stage A: histogram (scores are >0 so float bits are uint-monotone)
    for (int i = tid; i < cnt; i += 256) {
        const unsigned u = __float_as_uint(cscore[b * CAP + i]);
        atomicAdd(&hist[u >> 20], 1);
    }
    __syncthreads();

    // Stage B: find threshold bin (serial walk, ~2048 iters, negligible)
    if (tid == 0) {
        int cum = 0, B = 0;
        for (int bin = NBIN - 1; bin >= 0; --bin) {
            cum += hist[bin];
            if (cum >= need) { B = bin; break; }
        }
        binB_sh = B;
    }
    __syncthreads();
    const int B = binB_sh;

    // Stage C: compact finalists (set-based; LDS-atomic order irrelevant)
    for (int i = tid; i < cnt; i += 256) {
        const float s_ = cscore[b * CAP + i];
        const unsigned u = __float_as_uint(s_);
        if ((int)(u >> 20) >= B) {
            const int p = atomicAdd(&nf_sh, 1);
            if (p < FCAP) { fsc[p] = s_; fid[p] = cidx[b * CAP + i]; }
        }
    }
    __syncthreads();
    int nf = nf_sh;
    if (nf > FCAP) nf = FCAP;

    // Stage D: one wave, exact iterative top-100 over finalists
    if (tid < 64) {
        const int lane = tid;
        for (int k = 0; k < KTOP; ++k) {
            if (k < need) {
                float bs = -FLT_MAX;
                int   bi = 0x7fffffff;
                int   bp = -1;
                for (int i = lane; i < nf; i += 64) {
                    const float s_ = fsc[i];
                    const int   id = fid[i];
                    if (s_ > bs || (s_ == bs && id < bi)) { bs = s_; bi = id; bp = i; }
                }
#pragma unroll
                for (int off = 32; off > 0; off >>= 1) {
                    const float os = __shfl_xor(bs, off);
                    const int   oi = __shfl_xor(bi, off);
                    const int   op = __shfl_xor(bp, off);
                    if (os > bs || (os == bs && oi < bi)) { bs = os; bi = oi; bp = op; }
                }
                // winner slot is only ever scanned by lane (bp&63): same-lane
                // LDS dependency, no cross-lane sync needed
                if (bp >= 0 && (bp & 63) == lane) fsc[bp] = -FLT_MAX;
                if (lane == 0) {
                    const int sidx = bi / HW;
                    const int sp   = bi - sidx * HW;
                    const int yy   = sp / W_;
                    const int xx   = sp - yy * W_;
                    const int sc_c = sidx < 0 ? 0 : (sidx > S_ - 1 ? S_ - 1 : sidx);
                    out[b * KTOP + k]                 = bs > 0.f ? bs : 0.f;
                    out[800 + (b * KTOP + k) * 2 + 0] = (float)xx / (float)W_;
                    out[800 + (b * KTOP + k) * 2 + 1] = (float)yy / (float)H_;
                    out[2400 + b * KTOP + k]          = sigma[sc_c];
                    out[3200 + b * KTOP + k]          = (float)sp;
                }
            } else if (lane == 0) {
                // cnt < 100 fallback (not expected for this input): NEG entries
                int flat = k - cnt; if (flat < 0) flat = 0;
                const int sidx = flat / HW;
                const int sp   = flat - sidx * HW;
                const int yy   = sp / W_;
                const int xx   = sp - yy * W_;
                const int sc_c = sidx < 0 ? 0 : (sidx > S_ - 1 ? S_ - 1 : sidx);
                out[b * KTOP + k]                 = 0.f;
                out[800 + (b * KTOP + k) * 2 + 0] = (float)xx / (float)W_;
                out[800 + (b * KTOP + k) * 2 + 1] = (float)yy / (float)H_;
                out[2400 + b * KTOP + k]          = sigma[sc_c];
                out[3200 + b * KTOP + k]          = (float)sp;
            }
        }
    }
}

__global__ void init_counts_kernel(int* counts)
{
    for (int i = threadIdx.x; i < B_ * CPAD; i += 256) counts[i] = 0;
}

extern "C" void kernel_launch(void* const* d_in, const int* in_sizes, int n_in,
                              void* d_out, int out_size, void* d_ws, size_t ws_size,
                              hipStream_t stream)
{
    const float* feats = (const float*)d_in[0];
    const float* sigma = (const float*)d_in[1];
    const float* w1    = (const float*)d_in[2];
    const float* b1    = (const float*)d_in[3];
    const float* w2    = (const float*)d_in[4];
    const float* b2    = (const float*)d_in[5];
    float* out = (float*)d_out;

    char* ws = (char*)d_ws;
    float* resp   = (float*)ws;
    int*   counts = (int*)(ws + (size_t)NPIX * 4);                       // B_*CPAD ints
    float* cscore = (float*)(ws + (size_t)NPIX * 4 + (size_t)B_ * CPAD * 4);
    int*   cidx   = (int*)(ws + (size_t)NPIX * 4 + (size_t)B_ * CPAD * 4
                              + (size_t)B_ * CAP * 4);
    float* w1t_g  = (float*)(ws + (size_t)NPIX * 4 + (size_t)B_ * CPAD * 4
                              + (size_t)B_ * CAP * 4 + (size_t)B_ * CAP * 4);

    init_counts_kernel<<<1, 256, 0, stream>>>(counts);
    transpose_w1_kernel<<<C_ * CH / 256, 256, 0, stream>>>(w1, w1t_g);
    resp_kernel<<<B_ * S_ * 96, 256, 0, stream>>>(feats, sigma, w1t_g, b1, w2, b2, resp);
    peak_kernel<<<NPIX / 256, 256, 0, stream>>>(resp, counts, cscore, cidx);
    topk_kernel<<<B_, 256, 0, stream>>>(cscore, cidx, counts, sigma, out);
}

// Round 10
// 362.356 us; speedup vs baseline: 4.0495x; 1.1675x over previous
//
#include <hip/hip_runtime.h>
#include <cstdint>
#include <cfloat>
#include <cstddef>

#define C_   128
#define CH   64
#define B_   8
#define S_   6
#define H_   128
#define W_   192
#define HW   (H_*W_)          /* 24576 */
#define SHW  (S_*HW)          /* 147456 */
#define NPIX (B_*SHW)         /* 1179648 */
#define KTOP 100
#define CAP  6144
#define NEGV (-1e9f)
#define EPSV (1e-6f)
#define CPAD 64               /* counts padded: one counter per 256B */
#define NBIN 2048
#define FCAP 4096

// ---------------------------------------------------------------------------
// K0: prep — transpose w1 (CHxC) -> w1t_g (CxCH) for scalar-pipe uniform
// reads (Round-8 win) + zero the padded counts. One kernel, 32 blocks.
// ---------------------------------------------------------------------------
__global__ __launch_bounds__(256) void prep_kernel(
    const float* __restrict__ w1, float* __restrict__ w1t_g,
    int* __restrict__ counts)
{
    const int i = blockIdx.x * 256 + threadIdx.x;   // grid covers C_*CH = 8192
    if (i < C_ * CH) {
        const int c = i >> 6;           // [0,128)
        const int o = i & (CH - 1);     // [0,64)
        w1t_g[i] = w1[o * C_ + c];
    }
    if (i < B_ * CPAD) counts[i] = 0;
}

// ---------------------------------------------------------------------------
// K1 v4 (unchanged from Round 9, ~266us): resp = sigma^2*(w2.relu(W1@f+b1)+b2)
// 1 pixel/thread, w1t scalar-pipe uniform reads. Bit-exact FMA chain
// (c ascending, o ascending). NO launch_bounds min-wave arg (Round-6 spill).
// ---------------------------------------------------------------------------
__global__ __launch_bounds__(256) void resp_kernel(
    const float* __restrict__ feats, const float* __restrict__ sigma,
    const float* __restrict__ w1t_g, const float* __restrict__ b1,
    const float* __restrict__ w2, const float* __restrict__ b2,
    float* __restrict__ resp)
{
    __shared__ float b1s[CH];
    __shared__ float w2s[CH];
    if (threadIdx.x < CH) {
        b1s[threadIdx.x] = b1[threadIdx.x];
        w2s[threadIdx.x] = w2[threadIdx.x];
    }
    __syncthreads();

    const int plane = blockIdx.x / 96;              // b*S + s   (96 blk/plane)
    const int p0    = (blockIdx.x % 96) * 256 + threadIdx.x;
    const float* fp = feats + (size_t)plane * (size_t)(C_ * HW) + p0;

    float acc[CH];
#pragma unroll
    for (int o = 0; o < CH; ++o) acc[o] = 0.f;

#pragma unroll 4
    for (int c = 0; c < C_; ++c) {
        const float f = fp[(size_t)c * HW];         // wave: 64x4B contiguous
#pragma unroll
        for (int o = 0; o < CH; o += 4) {
            // block-uniform address -> scalar load; w.* are SGPR operands
            const float4 w = *reinterpret_cast<const float4*>(
                &w1t_g[(c << 6) + o]);
            acc[o + 0] += w.x * f;
            acc[o + 1] += w.y * f;
            acc[o + 2] += w.z * f;
            acc[o + 3] += w.w * f;
        }
    }

    const float b2v = b2[0];
    float rx = b2v;
#pragma unroll
    for (int o = 0; o < CH; ++o) {
        const float hx = fmaxf(acc[o] + b1s[o], 0.f);
        rx += w2s[o] * hx;
    }
    const int   s   = plane % S_;
    const float sg  = sigma[s];
    resp[(size_t)plane * HW + p0] = rx * (sg * sg);
}

// ---------------------------------------------------------------------------
// K2: 3x3x3 local max -> candidates. Per-block LDS aggregation, ONE global
// atomic per block, counters padded to separate cache lines (Round-5 fix).
// ---------------------------------------------------------------------------
__global__ __launch_bounds__(256) void peak_kernel(
    const float* __restrict__ resp, int* __restrict__ counts,
    float* __restrict__ cscore, int* __restrict__ cidx)
{
    __shared__ int   lcount;
    __shared__ int   lbase;
    __shared__ float lsc[256];
    __shared__ int   lsi[256];

    if (threadIdx.x == 0) lcount = 0;
    __syncthreads();

    const int gid = blockIdx.x * 256 + threadIdx.x;   // grid covers NPIX exactly
    const int b   = gid / SHW;                        // uniform per block
    const int rem = gid - b * SHW;
    const int s   = rem / HW;                         // uniform per block
    const int p   = rem - s * HW;
    const int y   = p / W_;
    const int x   = p - y * W_;

    const float v = resp[gid];
    bool win = false;
    if (v > 0.f) {                         // is_peak requires resp > 0
        float m = NEGV;
        for (int ds = -1; ds <= 1; ++ds) {
            const int ss = s + ds;
            if (ss < 0 || ss >= S_) continue;   // NEG padding contributes nothing
            for (int dy = -1; dy <= 1; ++dy) {
                const int yy = y + dy;
                if (yy < 0 || yy >= H_) continue;
                for (int dx = -1; dx <= 1; ++dx) {
                    const int xx = x + dx;
                    if (xx < 0 || xx >= W_) continue;
                    m = fmaxf(m, resp[(b * S_ + ss) * HW + yy * W_ + xx]);
                }
            }
        }
        // m includes v itself, so m >= v and |v - m| = m - v
        win = (m - v < EPSV);
    }

    if (win) {
        const int lp = atomicAdd(&lcount, 1);   // LDS atomic — cheap
        lsc[lp] = v;
        lsi[lp] = s * HW + p;
    }
    __syncthreads();
    if (threadIdx.x == 0 && lcount > 0)
        lbase = atomicAdd(&counts[b * CPAD], lcount);  // one atomic/block, padded line
    __syncthreads();
    const int n = lcount;
    for (int i = threadIdx.x; i < n; i += 256) {
        const int pos = lbase + i;
        if (pos < CAP) {
            cscore[b * CAP + pos] = lsc[i];
            cidx[b * CAP + pos]   = lsi[i];
        }
    }
}

// ---------------------------------------------------------------------------
// K3 v3: histogram radix-select. Round-10 fix: Stage B threshold-bin search
// parallelized (per-thread 8-bin partials + 256-wide Hillis-Steele scan);
// replaces the single-thread 2048-iteration LDS walk (~115us on critical
// path of all 8 blocks). Selection semantics IDENTICAL (same threshold bin,
// same finalist set, same (score desc, idx asc) tie-break as lax.top_k).
// ---------------------------------------------------------------------------
__global__ __launch_bounds__(256) void topk_kernel(
    const float* __restrict__ cscore, const int* __restrict__ cidx,
    const int* __restrict__ counts, const float* __restrict__ sigma,
    float* __restrict__ out)
{
    __shared__ int   hist[NBIN];
    __shared__ int   psum[256];
    __shared__ float fsc[FCAP];
    __shared__ int   fid[FCAP];
    __shared__ int   nf_sh;
    __shared__ int   binB_sh;

    const int b   = blockIdx.x;
    const int tid = threadIdx.x;

    int cnt = counts[b * CPAD];
    if (cnt > CAP) cnt = CAP;
    const int need = cnt < KTOP ? cnt : KTOP;

    for (int i = tid; i < NBIN; i += 256) hist[i] = 0;
    if (tid == 0) { nf_sh = 0; binB_sh = 0; }
    __syncthreads();

    // Stage A: histogram (scores are >0 so float bits are uint-monotone)
    for (int i = tid; i < cnt; i += 256) {
        const unsigned u = __float_as_uint(cscore[b * CAP + i]);
        atomicAdd(&hist[u >> 20], 1);
    }
    __syncthreads();

    // Stage B (parallel): thread t owns descending-bin chunk
    // bins {2047-8t-j, j=0..7}; scan partials; unique crossing thread
    // writes the threshold bin containing rank `need`.
    int part = 0;
#pragma unroll
    for (int j = 0; j < 8; ++j) part += hist[2047 - (tid * 8 + j)];
    psum[tid] = part;
    __syncthreads();
    int v = part;
    for (int off = 1; off < 256; off <<= 1) {
        const int add = (tid >= off) ? psum[tid - off] : 0;
        __syncthreads();
        v += add;
        psum[tid] = v;
        __syncthreads();
    }
    const int base = v - part;          // candidates in higher chunks
    if (need > 0 && base < need && need <= v) {
        int cum = base, Bv = 2047 - tid * 8 - 7;
#pragma unroll
        for (int j = 0; j < 8; ++j) {
            const int bin = 2047 - (tid * 8 + j);
            cum += hist[bin];
            if (cum >= need) { Bv = bin; break; }
        }
        binB_sh = Bv;                    // exactly one thread writes
    }
    __syncthreads();
    const int B = binB_sh;

    // Stage C: compact finalists (set-based; LDS-atomic order irrelevant)
    for (int i = tid; i < cnt; i += 256) {
        const float s_ = cscore[b * CAP + i];
        const unsigned u = __float_as_uint(s_);
        if ((int)(u >> 20) >= B) {
            const int p = atomicAdd(&nf_sh, 1);
            if (p < FCAP) { fsc[p] = s_; fid[p] = cidx[b * CAP + i]; }
        }
    }
    __syncthreads();
    int nf = nf_sh;
    if (nf > FCAP) nf = FCAP;

    // Stage D: one wave, exact iterative top-100 over finalists
    if (tid < 64) {
        const int lane = tid;
        for (int k = 0; k < KTOP; ++k) {
            if (k < need) {
                float bs = -FLT_MAX;
                int   bi = 0x7fffffff;
                int   bp = -1;
                for (int i = lane; i < nf; i += 64) {
                    const float s_ = fsc[i];
                    const int   id = fid[i];
                    if (s_ > bs || (s_ == bs && id < bi)) { bs = s_; bi = id; bp = i; }
                }
#pragma unroll
                for (int off = 32; off > 0; off >>= 1) {
                    const float os = __shfl_xor(bs, off);
                    const int   oi = __shfl_xor(bi, off);
                    const int   op = __shfl_xor(bp, off);
                    if (os > bs || (os == bs && oi < bi)) { bs = os; bi = oi; bp = op; }
                }
                // winner slot is only ever scanned by lane (bp&63): same-lane
                // LDS dependency, no cross-lane sync needed
                if (bp >= 0 && (bp & 63) == lane) fsc[bp] = -FLT_MAX;
                if (lane == 0) {
                    const int sidx = bi / HW;
                    const int sp   = bi - sidx * HW;
                    const int yy   = sp / W_;
                    const int xx   = sp - yy * W_;
                    const int sc_c = sidx < 0 ? 0 : (sidx > S_ - 1 ? S_ - 1 : sidx);
                    out[b * KTOP + k]                 = bs > 0.f ? bs : 0.f;
                    out[800 + (b * KTOP + k) * 2 + 0] = (float)xx / (float)W_;
                    out[800 + (b * KTOP + k) * 2 + 1] = (float)yy / (float)H_;
                    out[2400 + b * KTOP + k]          = sigma[sc_c];
                    out[3200 + b * KTOP + k]          = (float)sp;
                }
            } else if (lane == 0) {
                // cnt < 100 fallback (not expected for this input): NEG entries
                int flat = k - cnt; if (flat < 0) flat = 0;
                const int sidx = flat / HW;
                const int sp   = flat - sidx * HW;
                const int yy   = sp / W_;
                const int xx   = sp - yy * W_;
                const int sc_c = sidx < 0 ? 0 : (sidx > S_ - 1 ? S_ - 1 : sidx);
                out[b * KTOP + k]                 = 0.f;
                out[800 + (b * KTOP + k) * 2 + 0] = (float)xx / (float)W_;
                out[800 + (b * KTOP + k) * 2 + 1] = (float)yy / (float)H_;
                out[2400 + b * KTOP + k]          = sigma[sc_c];
                out[3200 + b * KTOP + k]          = (float)sp;
            }
        }
    }
}

extern "C" void kernel_launch(void* const* d_in, const int* in_sizes, int n_in,
                              void* d_out, int out_size, void* d_ws, size_t ws_size,
                              hipStream_t stream)
{
    const float* feats = (const float*)d_in[0];
    const float* sigma = (const float*)d_in[1];
    const float* w1    = (const float*)d_in[2];
    const float* b1    = (const float*)d_in[3];
    const float* w2    = (const float*)d_in[4];
    const float* b2    = (const float*)d_in[5];
    float* out = (float*)d_out;

    char* ws = (char*)d_ws;
    float* resp   = (float*)ws;
    int*   counts = (int*)(ws + (size_t)NPIX * 4);                       // B_*CPAD ints
    float* cscore = (float*)(ws + (size_t)NPIX * 4 + (size_t)B_ * CPAD * 4);
    int*   cidx   = (int*)(ws + (size_t)NPIX * 4 + (size_t)B_ * CPAD * 4
                              + (size_t)B_ * CAP * 4);
    float* w1t_g  = (float*)(ws + (size_t)NPIX * 4 + (size_t)B_ * CPAD * 4
                              + (size_t)B_ * CAP * 4 + (size_t)B_ * CAP * 4);

    prep_kernel<<<C_ * CH / 256, 256, 0, stream>>>(w1, w1t_g, counts);
    resp_kernel<<<B_ * S_ * 96, 256, 0, stream>>>(feats, sigma, w1t_g, b1, w2, b2, resp);
    peak_kernel<<<NPIX / 256, 256, 0, stream>>>(resp, counts, cscore, cidx);
    topk_kernel<<<B_, 256, 0, stream>>>(cscore, cidx, counts, sigma, out);
}